// Round 1
// baseline (5326.460 us; speedup 1.0000x reference)
//
#include <hip/hip_runtime.h>
#include <cstdint>
#include <cstddef>

// ---- problem constants (from reference) ----
constexpr int Bn     = 512;
constexpr int Dd     = 11;
constexpr int LEAVES = 1024;      // 1 << (D-1)
constexpr int NINT   = 1023;
constexpr int FLEAF  = 64;
constexpr int FINT   = 32;
constexpr int Hh     = 128;
constexpr int NHIDl  = 4;
constexpr int OUTC   = 33;        // 1 + DV
constexpr int KINT   = FINT + 2 * OUTC;  // 98

// ---- kernel config ----
#define THREADS 256
constexpr int M_TILE   = 64;      // rows per block
constexpr int M_STRIDE = 68;      // padded (68*4B = 272B, 16B-aligned rows, odd*4 groups)

struct Smem {
  float actT[Hh][M_STRIDE];  // activations, transposed: actT[k][m]  (34,816 B)
  float W[Hh * Hh];          // current layer weights                (65,536 B)
  float bias[Hh];            //                                      (512 B)
};
// total ~100.9 KB -> 1 block/CU (LDS-bound); 256 thr = 1 wave/SIMD, ILP-reliant.

// One dense layer: actT[0..K-1][*] -> ReLU(actT[0..127][*]), weights Wg row-major (K,128).
__device__ __forceinline__ void dense_layer(Smem& s, const float* __restrict__ Wg,
                                            const float* __restrict__ bg, int K) {
  const int tid = threadIdx.x;
  // stage weights: K*128 floats (always %4==0) via float4
  const int n4 = (K * Hh) >> 2;
  const float4* Wg4 = (const float4*)Wg;
  float4* Ws4 = (float4*)s.W;
  for (int i = tid; i < n4; i += THREADS) Ws4[i] = Wg4[i];
  if (tid < Hh) s.bias[tid] = bg[tid];
  __syncthreads();

  // thread tile: 4 rows (m0..m0+3) x 8 cols (n0..n0+7)
  const int m0 = (tid & 15) << 2;
  const int n0 = (tid >> 4) << 3;
  float acc[8][4];
#pragma unroll
  for (int ni = 0; ni < 8; ++ni) {
    float bv = s.bias[n0 + ni];
#pragma unroll
    for (int mi = 0; mi < 4; ++mi) acc[ni][mi] = bv;
  }

  for (int k = 0; k < K; ++k) {
    float4 a  = *(const float4*)&s.actT[k][m0];
    float4 w0 = *(const float4*)&s.W[k * Hh + n0];
    float4 w1 = *(const float4*)&s.W[k * Hh + n0 + 4];
    float av[4] = {a.x, a.y, a.z, a.w};
    float wv[8] = {w0.x, w0.y, w0.z, w0.w, w1.x, w1.y, w1.z, w1.w};
#pragma unroll
    for (int ni = 0; ni < 8; ++ni)
#pragma unroll
      for (int mi = 0; mi < 4; ++mi)
        acc[ni][mi] = fmaf(av[mi], wv[ni], acc[ni][mi]);
  }
  __syncthreads();  // all reads of actT/W done before overwrite

#pragma unroll
  for (int ni = 0; ni < 8; ++ni) {
    float4 o;
    o.x = fmaxf(acc[ni][0], 0.f);
    o.y = fmaxf(acc[ni][1], 0.f);
    o.z = fmaxf(acc[ni][2], 0.f);
    o.w = fmaxf(acc[ni][3], 0.f);
    *(float4*)&s.actT[n0 + ni][m0] = o;
  }
}

// Output layer: (64 x 128) @ (128 x 33) + bias, linear, written to global.
__device__ __forceinline__ void out_layer(Smem& s, const float* __restrict__ Wg,
                                          const float* __restrict__ bg,
                                          float* __restrict__ outg, int row_base) {
  const int tid = threadIdx.x;
  for (int i = tid; i < Hh * OUTC; i += THREADS) s.W[i] = Wg[i];
  if (tid < OUTC) s.bias[tid] = bg[tid];
  __syncthreads();

  for (int p = tid; p < M_TILE * OUTC; p += THREADS) {
    int m = p / OUTC;
    int o = p - m * OUTC;
    float acc = s.bias[o];
#pragma unroll 4
    for (int k = 0; k < Hh; ++k)
      acc = fmaf(s.actT[k][m], s.W[k * OUTC + o], acc);
    outg[(size_t)(row_base + m) * OUTC + o] = acc;
  }
}

__global__ __launch_bounds__(THREADS, 1)
void leaf_kernel(const float* __restrict__ X,
                 const float* __restrict__ W_in, const float* __restrict__ b_in,
                 const float* __restrict__ W_hid, const float* __restrict__ b_hid,
                 const float* __restrict__ W_out, const float* __restrict__ b_out,
                 float* __restrict__ out) {
  __shared__ Smem s;
  const int row_base = blockIdx.x * M_TILE;
  // stage input transposed: actT[k][m] = X[row_base+m][k]
  for (int e = threadIdx.x; e < M_TILE * FLEAF; e += THREADS) {
    int m = e >> 6;        // /64
    int k = e & 63;
    s.actT[k][m] = X[(size_t)(row_base + m) * FLEAF + k];
  }
  dense_layer(s, W_in, b_in, FLEAF);
  for (int l = 0; l < NHIDl; ++l)
    dense_layer(s, W_hid + (size_t)l * Hh * Hh, b_hid + (size_t)l * Hh, Hh);
  out_layer(s, W_out, b_out, out, row_base);
}

__global__ __launch_bounds__(THREADS, 1)
void int_kernel(const float* __restrict__ feat, const float* __restrict__ prev,
                const float* __restrict__ W_in, const float* __restrict__ b_in,
                const float* __restrict__ W_hid, const float* __restrict__ b_hid,
                const float* __restrict__ W_out, const float* __restrict__ b_out,
                float* __restrict__ out, int n, int logn) {
  __shared__ Smem s;
  const int row_base = blockIdx.x * M_TILE;
  // input = concat(int_feat[b, (n-1)+i, 0:32], prev[b, 2i, 0:33], prev[b, 2i+1, 0:33])
  for (int e = threadIdx.x; e < M_TILE * KINT; e += THREADS) {
    int m = e / KINT;
    int k = e - m * KINT;
    int row = row_base + m;        // = b*n + i
    int b = row >> logn;
    int i = row & (n - 1);
    float v;
    if (k < FINT) {
      v = feat[((size_t)b * NINT + (n - 1) + i) * FINT + k];
    } else {
      // children of node i are prev nodes 2i, 2i+1 -> contiguous 66 floats
      v = prev[((size_t)b * (n << 1) + (i << 1)) * OUTC + (k - FINT)];
    }
    s.actT[k][m] = v;
  }
  dense_layer(s, W_in, b_in, KINT);
  for (int l = 0; l < NHIDl; ++l)
    dense_layer(s, W_hid + (size_t)l * Hh * Hh, b_hid + (size_t)l * Hh, Hh);
  out_layer(s, W_out, b_out, out, row_base);
}

__global__ void gather_kernel(const float* __restrict__ buf, float* __restrict__ out) {
  int b = blockIdx.x * blockDim.x + threadIdx.x;
  if (b < Bn) out[b] = buf[(size_t)b * OUTC];
}

extern "C" void kernel_launch(void* const* d_in, const int* in_sizes, int n_in,
                              void* d_out, int out_size, void* d_ws, size_t ws_size,
                              hipStream_t stream) {
  const float* leaf_feat = (const float*)d_in[0];
  const float* int_feat  = (const float*)d_in[1];
  const float* lW_in  = (const float*)d_in[2];
  const float* lb_in  = (const float*)d_in[3];
  const float* lW_hid = (const float*)d_in[4];
  const float* lb_hid = (const float*)d_in[5];
  const float* lW_out = (const float*)d_in[6];
  const float* lb_out = (const float*)d_in[7];
  const float* iW_in  = (const float*)d_in[8];
  const float* ib_in  = (const float*)d_in[9];
  const float* iW_hid = (const float*)d_in[10];
  const float* ib_hid = (const float*)d_in[11];
  const float* iW_out = (const float*)d_in[12];
  const float* ib_out = (const float*)d_in[13];
  float* out = (float*)d_out;

  // ws layout: bufA = 512*1024*33 floats (69.2 MB), bufB = 512*512*33 floats (34.6 MB)
  float* bufA = (float*)d_ws;
  float* bufB = bufA + (size_t)Bn * LEAVES * OUTC;

  // leaf stage: 524288 rows
  leaf_kernel<<<(Bn * LEAVES) / M_TILE, THREADS, 0, stream>>>(
      leaf_feat, lW_in, lb_in, lW_hid, lb_hid, lW_out, lb_out, bufA);

  // internal levels d = 9 .. 0, ping-pong A/B
  float* prev = bufA;
  float* next = bufB;
  for (int d = Dd - 2; d >= 0; --d) {
    int n = 1 << d;
    int blocks = (Bn * n) / M_TILE;  // 8n, integer for all n>=1
    int_kernel<<<blocks, THREADS, 0, stream>>>(
        int_feat, prev, iW_in, ib_in, iW_hid, ib_hid, iW_out, ib_out, next, n, d);
    float* t = prev; prev = next; next = t;
  }

  gather_kernel<<<1, Bn, 0, stream>>>(prev, out);
}

// Round 2
// 1019.821 us; speedup vs baseline: 5.2229x; 5.2229x over previous
//
#include <hip/hip_runtime.h>
#include <cstdint>
#include <cstddef>

// ---- problem constants ----
constexpr int Bn     = 512;
constexpr int Dd     = 11;
constexpr int LEAVES = 1024;
constexpr int NINT   = 1023;
constexpr int FLEAF  = 64;
constexpr int FINT   = 32;
constexpr int Hh     = 128;
constexpr int NHIDl  = 4;
constexpr int OUTC   = 33;
constexpr int KINT   = FINT + 2 * OUTC;   // 98

// ---- MFMA config ----
#define THREADS 256
constexpr int M_TILE = 64;
constexpr int KSTR   = 136;               // k-stride (128 + 8 pad) -> rows 272B, 16B aligned, bank-shift 4
constexpr int MATSZ  = 128 * KSTR;        // ushorts per half-matrix slot (hi or lo)

using short8 = __attribute__((ext_vector_type(8))) short;
using f32x4  = __attribute__((ext_vector_type(4))) float;

__device__ __forceinline__ unsigned short f2bf(float f) {
  unsigned int u = __float_as_uint(f);
  u += 0x7fff + ((u >> 16) & 1);          // round-to-nearest-even
  return (unsigned short)(u >> 16);
}
__device__ __forceinline__ float bf2f(unsigned short h) {
  return __uint_as_float(((unsigned int)h) << 16);
}

// One dense layer on a 64-row tile, in place in LDS.
// A (hi/lo bf16) in LDS [64][KSTR]; WT (hi/lo) global [128][KSTR] n-major k-contig;
// bias fp32[128]. Computes ReLU(A @ W + b) -> back into Ah/Al cols 0..127.
template <int KCHUNKS>
__device__ __forceinline__ void dense_layer_mfma(
    unsigned short* Ah, unsigned short* Al,
    const unsigned short* __restrict__ WTh, const unsigned short* __restrict__ WTl,
    const float* __restrict__ bias)
{
  const int tid  = threadIdx.x;
  const int wave = tid >> 6;
  const int lane = tid & 63;
  const int quad = lane >> 4;
  const int l16  = lane & 15;
  const int nbase = wave * 32;

  f32x4 c[4][2];
#pragma unroll
  for (int mt = 0; mt < 4; ++mt)
#pragma unroll
    for (int nt = 0; nt < 2; ++nt) c[mt][nt] = (f32x4){0.f, 0.f, 0.f, 0.f};

#pragma unroll
  for (int kc = 0; kc < KCHUNKS; ++kc) {
    const int k0 = kc * 32 + quad * 8;
    short8 a_h[4], a_l[4];
#pragma unroll
    for (int mt = 0; mt < 4; ++mt) {
      const int row = mt * 16 + l16;
      a_h[mt] = *(const short8*)&Ah[row * KSTR + k0];
      a_l[mt] = *(const short8*)&Al[row * KSTR + k0];
    }
    short8 b_h[2], b_l[2];
#pragma unroll
    for (int nt = 0; nt < 2; ++nt) {
      const int n = nbase + nt * 16 + l16;
      b_h[nt] = *(const short8*)&WTh[n * KSTR + k0];
      b_l[nt] = *(const short8*)&WTl[n * KSTR + k0];
    }
#pragma unroll
    for (int nt = 0; nt < 2; ++nt)
#pragma unroll
      for (int mt = 0; mt < 4; ++mt) {
        c[mt][nt] = __builtin_amdgcn_mfma_f32_16x16x32_bf16(a_h[mt], b_h[nt], c[mt][nt], 0, 0, 0);
        c[mt][nt] = __builtin_amdgcn_mfma_f32_16x16x32_bf16(a_l[mt], b_h[nt], c[mt][nt], 0, 0, 0);
        c[mt][nt] = __builtin_amdgcn_mfma_f32_16x16x32_bf16(a_h[mt], b_l[nt], c[mt][nt], 0, 0, 0);
      }
  }
  __syncthreads();  // all A reads done before in-place overwrite

#pragma unroll
  for (int nt = 0; nt < 2; ++nt) {
    const int n = nbase + nt * 16 + l16;
    const float bv = bias[n];
#pragma unroll
    for (int mt = 0; mt < 4; ++mt)
#pragma unroll
      for (int r = 0; r < 4; ++r) {
        const int row = mt * 16 + quad * 4 + r;
        float v = c[mt][nt][r] + bv;
        v = fmaxf(v, 0.f);
        const unsigned short h = f2bf(v);
        const unsigned short lo = f2bf(v - bf2f(h));
        Ah[row * KSTR + n] = h;
        Al[row * KSTR + n] = lo;
      }
  }
  __syncthreads();
}

// Output layer: [64 x 128] @ [128 x 33] + bias -> global fp32 (stride 33).
__device__ __forceinline__ void out_layer_mfma(
    const unsigned short* Ah, const unsigned short* Al,
    const unsigned short* __restrict__ WTh, const unsigned short* __restrict__ WTl,
    const float* __restrict__ bias, float* __restrict__ outg, int row_base)
{
  const int tid  = threadIdx.x;
  const int wave = tid >> 6;
  const int lane = tid & 63;
  const int quad = lane >> 4;
  const int l16  = lane & 15;
  if (wave >= 3) return;  // 48 padded cols = 3 n-tiles

  f32x4 c[4];
#pragma unroll
  for (int mt = 0; mt < 4; ++mt) c[mt] = (f32x4){0.f, 0.f, 0.f, 0.f};

#pragma unroll
  for (int kc = 0; kc < 4; ++kc) {
    const int k0 = kc * 32 + quad * 8;
    const int n  = wave * 16 + l16;
    const short8 b_h = *(const short8*)&WTh[n * KSTR + k0];
    const short8 b_l = *(const short8*)&WTl[n * KSTR + k0];
#pragma unroll
    for (int mt = 0; mt < 4; ++mt) {
      const int row = mt * 16 + l16;
      const short8 a_h = *(const short8*)&Ah[row * KSTR + k0];
      const short8 a_l = *(const short8*)&Al[row * KSTR + k0];
      c[mt] = __builtin_amdgcn_mfma_f32_16x16x32_bf16(a_h, b_h, c[mt], 0, 0, 0);
      c[mt] = __builtin_amdgcn_mfma_f32_16x16x32_bf16(a_l, b_h, c[mt], 0, 0, 0);
      c[mt] = __builtin_amdgcn_mfma_f32_16x16x32_bf16(a_h, b_l, c[mt], 0, 0, 0);
    }
  }

  const int n = wave * 16 + l16;
  if (n < OUTC) {
    const float bv = bias[n];
#pragma unroll
    for (int mt = 0; mt < 4; ++mt)
#pragma unroll
      for (int r = 0; r < 4; ++r) {
        const int row = mt * 16 + quad * 4 + r;
        outg[(size_t)(row_base + row) * OUTC + n] = c[mt][r] + bv;
      }
  }
}

__global__ __launch_bounds__(THREADS, 2)
void leaf_kernel(const float* __restrict__ X,
                 const unsigned short* __restrict__ warena,
                 const float* __restrict__ barena,
                 float* __restrict__ out)
{
  __shared__ unsigned short Ah[M_TILE * KSTR];
  __shared__ unsigned short Al[M_TILE * KSTR];
  const int row_base = blockIdx.x * M_TILE;
  const int tid = threadIdx.x;

  // stage input: 64 rows x 64 fp32, coalesced float4, split hi/lo
  for (int e = tid; e < M_TILE * (FLEAF / 4); e += THREADS) {
    const int r  = e >> 4;           // /16 float4s per row
    const int k0 = (e & 15) << 2;
    const float4 v = *(const float4*)&X[(size_t)(row_base + r) * FLEAF + k0];
    const float vv[4] = {v.x, v.y, v.z, v.w};
    unsigned short hs[4], ls[4];
#pragma unroll
    for (int j = 0; j < 4; ++j) {
      hs[j] = f2bf(vv[j]);
      ls[j] = f2bf(vv[j] - bf2f(hs[j]));
    }
    *(ushort4*)&Ah[r * KSTR + k0] = *(ushort4*)hs;
    *(ushort4*)&Al[r * KSTR + k0] = *(ushort4*)ls;
  }
  __syncthreads();

  dense_layer_mfma<2>(Ah, Al, warena + 0 * 2 * MATSZ, warena + 0 * 2 * MATSZ + MATSZ, barena + 0 * 128);
#pragma unroll
  for (int l = 0; l < NHIDl; ++l) {
    const int id = 1 + l;
    dense_layer_mfma<4>(Ah, Al, warena + id * 2 * MATSZ, warena + id * 2 * MATSZ + MATSZ, barena + id * 128);
  }
  out_layer_mfma(Ah, Al, warena + 5 * 2 * MATSZ, warena + 5 * 2 * MATSZ + MATSZ, barena + 5 * 128, out, row_base);
}

__global__ __launch_bounds__(THREADS, 2)
void int_kernel(const float* __restrict__ feat, const float* __restrict__ prev,
                const unsigned short* __restrict__ warena,
                const float* __restrict__ barena,
                float* __restrict__ out, int n, int logn)
{
  __shared__ unsigned short Ah[M_TILE * KSTR];
  __shared__ unsigned short Al[M_TILE * KSTR];
  const int row_base = blockIdx.x * M_TILE;
  const int tid = threadIdx.x;

  // stage: concat(feat[b, n-1+i, 0:32], prev children 66 floats), zero-pad to 128
  for (int e = tid; e < M_TILE * KINT; e += THREADS) {
    const int m = e / KINT;
    const int k = e - m * KINT;
    const int row = row_base + m;
    const int b = row >> logn;
    const int i = row & (n - 1);
    float v;
    if (k < FINT) {
      v = feat[((size_t)b * NINT + (n - 1) + i) * FINT + k];
    } else {
      v = prev[((size_t)b * (n << 1) + (i << 1)) * OUTC + (k - FINT)];
    }
    const unsigned short h = f2bf(v);
    Ah[m * KSTR + k] = h;
    Al[m * KSTR + k] = f2bf(v - bf2f(h));
  }
  for (int e = tid; e < M_TILE * (Hh - KINT); e += THREADS) {
    const int m = e / (Hh - KINT);
    const int k = KINT + (e - m * (Hh - KINT));
    Ah[m * KSTR + k] = 0;
    Al[m * KSTR + k] = 0;
  }
  __syncthreads();

  dense_layer_mfma<4>(Ah, Al, warena + 6 * 2 * MATSZ, warena + 6 * 2 * MATSZ + MATSZ, barena + 6 * 128);
#pragma unroll
  for (int l = 0; l < NHIDl; ++l) {
    const int id = 7 + l;
    dense_layer_mfma<4>(Ah, Al, warena + id * 2 * MATSZ, warena + id * 2 * MATSZ + MATSZ, barena + id * 128);
  }
  out_layer_mfma(Ah, Al, warena + 11 * 2 * MATSZ, warena + 11 * 2 * MATSZ + MATSZ, barena + 11 * 128, out, row_base);
}

// Pre-transpose + hi/lo split all 12 weight matrices into WT[n][k] (k-contig, padded),
// and pack biases into a 12x128 fp32 arena (zero-padded).
__global__ void prep_kernel(const float* __restrict__ lW_in, const float* __restrict__ lW_hid,
                            const float* __restrict__ lW_out, const float* __restrict__ lb_in,
                            const float* __restrict__ lb_hid, const float* __restrict__ lb_out,
                            const float* __restrict__ iW_in, const float* __restrict__ iW_hid,
                            const float* __restrict__ iW_out, const float* __restrict__ ib_in,
                            const float* __restrict__ ib_hid, const float* __restrict__ ib_out,
                            unsigned short* __restrict__ warena, float* __restrict__ barena)
{
  const int id = blockIdx.y;
  const float* W; const float* bsrc; int K, N;
  if (id == 0)       { W = lW_in;                     bsrc = lb_in;               K = FLEAF; N = Hh; }
  else if (id <= 4)  { W = lW_hid + (id - 1) * Hh*Hh; bsrc = lb_hid + (id-1)*Hh;  K = Hh;    N = Hh; }
  else if (id == 5)  { W = lW_out;                    bsrc = lb_out;              K = Hh;    N = OUTC; }
  else if (id == 6)  { W = iW_in;                     bsrc = ib_in;               K = KINT;  N = Hh; }
  else if (id <= 10) { W = iW_hid + (id - 7) * Hh*Hh; bsrc = ib_hid + (id-7)*Hh;  K = Hh;    N = Hh; }
  else               { W = iW_out;                    bsrc = ib_out;              K = Hh;    N = OUTC; }

  unsigned short* dsth = warena + id * 2 * MATSZ;
  unsigned short* dstl = dsth + MATSZ;

  const int e = blockIdx.x * THREADS + threadIdx.x;
  if (e < MATSZ) {
    const int nn = e / KSTR;
    const int kp = e - nn * KSTR;
    float val = 0.f;
    if (kp < K && nn < N) val = W[(size_t)kp * N + nn];
    const unsigned short h = f2bf(val);
    dsth[e] = h;
    dstl[e] = f2bf(val - bf2f(h));
  }
  if (blockIdx.x == 0 && threadIdx.x < 128) {
    const int t = threadIdx.x;
    barena[id * 128 + t] = (t < N) ? bsrc[t] : 0.f;
  }
}

__global__ void gather_kernel(const float* __restrict__ buf, float* __restrict__ out) {
  const int b = blockIdx.x * blockDim.x + threadIdx.x;
  if (b < Bn) out[b] = buf[(size_t)b * OUTC];
}

extern "C" void kernel_launch(void* const* d_in, const int* in_sizes, int n_in,
                              void* d_out, int out_size, void* d_ws, size_t ws_size,
                              hipStream_t stream) {
  const float* leaf_feat = (const float*)d_in[0];
  const float* int_feat  = (const float*)d_in[1];
  const float* lW_in  = (const float*)d_in[2];
  const float* lb_in  = (const float*)d_in[3];
  const float* lW_hid = (const float*)d_in[4];
  const float* lb_hid = (const float*)d_in[5];
  const float* lW_out = (const float*)d_in[6];
  const float* lb_out = (const float*)d_in[7];
  const float* iW_in  = (const float*)d_in[8];
  const float* ib_in  = (const float*)d_in[9];
  const float* iW_hid = (const float*)d_in[10];
  const float* ib_hid = (const float*)d_in[11];
  const float* iW_out = (const float*)d_in[12];
  const float* ib_out = (const float*)d_in[13];
  float* out = (float*)d_out;

  // ws: bufA (512*1024*33 f32) | bufB (512*512*33 f32) | warena (24*MATSZ u16) | barena (12*128 f32)
  float* bufA = (float*)d_ws;
  float* bufB = bufA + (size_t)Bn * LEAVES * OUTC;
  unsigned short* warena = (unsigned short*)(bufB + (size_t)Bn * (LEAVES / 2) * OUTC);
  float* barena = (float*)(warena + 24 * MATSZ);

  prep_kernel<<<dim3((MATSZ + THREADS - 1) / THREADS, 12), THREADS, 0, stream>>>(
      lW_in, lW_hid, lW_out, lb_in, lb_hid, lb_out,
      iW_in, iW_hid, iW_out, ib_in, ib_hid, ib_out, warena, barena);

  leaf_kernel<<<(Bn * LEAVES) / M_TILE, THREADS, 0, stream>>>(leaf_feat, warena, barena, bufA);

  float* prev = bufA;
  float* next = bufB;
  for (int d = Dd - 2; d >= 0; --d) {
    const int n = 1 << d;
    const int blocks = (Bn * n) / M_TILE;   // 8n
    int_kernel<<<blocks, THREADS, 0, stream>>>(int_feat, prev, warena, barena, next, n, d);
    float* t = prev; prev = next; next = t;
  }

  gather_kernel<<<1, Bn, 0, stream>>>(prev, out);
}

// Round 3
// 913.698 us; speedup vs baseline: 5.8296x; 1.1161x over previous
//
#include <hip/hip_runtime.h>
#include <cstdint>
#include <cstddef>

// ---- problem constants ----
constexpr int Bn     = 512;
constexpr int Dd     = 11;
constexpr int LEAVES = 1024;
constexpr int NINT   = 1023;
constexpr int FLEAF  = 64;
constexpr int FINT   = 32;
constexpr int Hh     = 128;
constexpr int OUTC   = 33;

#define THREADS 256
constexpr int KSTR  = 136;            // LDS/weight k-stride (u16): 272B rows, 16B aligned
constexpr int MATSZ = 128 * KSTR;     // u16 per half-matrix (hi or lo)

using short8 = __attribute__((ext_vector_type(8))) short;
using f32x4  = __attribute__((ext_vector_type(4))) float;

__device__ __forceinline__ unsigned int f2bf_rne_u(float f) {
  unsigned int u = __float_as_uint(f);
  u += 0x7fffu + ((u >> 16) & 1);
  return u;                            // bf16 in hi16
}
__device__ __forceinline__ unsigned short f2bf_rne(float f) {
  return (unsigned short)(f2bf_rne_u(f) >> 16);
}
__device__ __forceinline__ float bf2f(unsigned short h) {
  return __uint_as_float((unsigned int)h << 16);
}
__device__ __forceinline__ float trunc_bf(float a) {
  return __uint_as_float(__float_as_uint(a) & 0xffff0000u);
}
// hi(trunc) of a -> lo16, hi(trunc) of b -> hi16
__device__ __forceinline__ unsigned int pack_hi_trunc(float a, float b) {
  return (__float_as_uint(a) >> 16) | (__float_as_uint(b) & 0xffff0000u);
}
__device__ __forceinline__ unsigned int pack_lo_rne(float a, float b) {
  return (f2bf_rne_u(a) >> 16) | (f2bf_rne_u(b) & 0xffff0000u);
}

// Swapped-operand dense layer: D = W_tile x Act^T.
// A-operand = WT[n][k] (n=l16 row), B-operand = Act[m][k] (m=l16 col).
// D: col = m = l16, row = n = quad*4+reg  -> epilogue writes 4 consecutive n (k of next
// layer) per fragment -> packed b64 LDS writes. ReLU(Act @ W + bias) in place.
template <int KC, int MT>
__device__ __forceinline__ void dense_layer(
    unsigned short* Ah, unsigned short* Al,
    const unsigned short* __restrict__ WTh, const unsigned short* __restrict__ WTl,
    const float* __restrict__ bias)
{
  const int tid  = threadIdx.x;
  const int wave = tid >> 6;
  const int lane = tid & 63;
  const int quad = lane >> 4;
  const int l16  = lane & 15;
  const int nbase = wave * 32;

  // preload W-hi fragments (8 frags = 32 VGPR for KC=4) + bias
  short8 wh[2][KC];
#pragma unroll
  for (int nt = 0; nt < 2; ++nt) {
    const int n = nbase + nt * 16 + l16;
#pragma unroll
    for (int kc = 0; kc < KC; ++kc)
      wh[nt][kc] = *(const short8*)&WTh[n * KSTR + kc * 32 + quad * 8];
  }
  float4 bv[2];
#pragma unroll
  for (int nt = 0; nt < 2; ++nt)
    bv[nt] = *(const float4*)&bias[nbase + nt * 16 + quad * 4];

  f32x4 c[MT][2];
#pragma unroll
  for (int mt = 0; mt < MT; ++mt)
#pragma unroll
    for (int nt = 0; nt < 2; ++nt) c[mt][nt] = (f32x4){0.f, 0.f, 0.f, 0.f};

#pragma unroll
  for (int kc = 0; kc < KC; ++kc) {
    const int k0 = kc * 32 + quad * 8;
    short8 wl[2];
#pragma unroll
    for (int nt = 0; nt < 2; ++nt) {
      const int n = nbase + nt * 16 + l16;
      wl[nt] = *(const short8*)&WTl[n * KSTR + k0];
    }
    short8 ah[MT], al[MT];
#pragma unroll
    for (int mt = 0; mt < MT; ++mt) {
      ah[mt] = *(const short8*)&Ah[(mt * 16 + l16) * KSTR + k0];
      al[mt] = *(const short8*)&Al[(mt * 16 + l16) * KSTR + k0];
    }
    // grouped by term: consecutive MFMAs independent across tiles
#pragma unroll
    for (int mt = 0; mt < MT; ++mt)
#pragma unroll
      for (int nt = 0; nt < 2; ++nt)
        c[mt][nt] = __builtin_amdgcn_mfma_f32_16x16x32_bf16(wh[nt][kc], ah[mt], c[mt][nt], 0, 0, 0);
#pragma unroll
    for (int mt = 0; mt < MT; ++mt)
#pragma unroll
      for (int nt = 0; nt < 2; ++nt)
        c[mt][nt] = __builtin_amdgcn_mfma_f32_16x16x32_bf16(wh[nt][kc], al[mt], c[mt][nt], 0, 0, 0);
#pragma unroll
    for (int mt = 0; mt < MT; ++mt)
#pragma unroll
      for (int nt = 0; nt < 2; ++nt)
        c[mt][nt] = __builtin_amdgcn_mfma_f32_16x16x32_bf16(wl[nt], ah[mt], c[mt][nt], 0, 0, 0);
  }
  __syncthreads();  // all reads of Ah/Al done before in-place overwrite

#pragma unroll
  for (int mt = 0; mt < MT; ++mt) {
    const int m = mt * 16 + l16;
#pragma unroll
    for (int nt = 0; nt < 2; ++nt) {
      const int nb = nbase + nt * 16 + quad * 4;
      float v0 = fmaxf(c[mt][nt][0] + bv[nt].x, 0.f);
      float v1 = fmaxf(c[mt][nt][1] + bv[nt].y, 0.f);
      float v2 = fmaxf(c[mt][nt][2] + bv[nt].z, 0.f);
      float v3 = fmaxf(c[mt][nt][3] + bv[nt].w, 0.f);
      const unsigned int h0 = pack_hi_trunc(v0, v1);
      const unsigned int h1 = pack_hi_trunc(v2, v3);
      const unsigned int l0 = pack_lo_rne(v0 - trunc_bf(v0), v1 - trunc_bf(v1));
      const unsigned int l1 = pack_lo_rne(v2 - trunc_bf(v2), v3 - trunc_bf(v3));
      *(uint2*)&Ah[m * KSTR + nb] = make_uint2(h0, h1);
      *(uint2*)&Al[m * KSTR + nb] = make_uint2(l0, l1);
    }
  }
  __syncthreads();
}

// Output layer: [M x 128] @ [128 x 33] + bias (linear). Writes u16 hi/lo rows (stride 33)
// to outH/outL (global or LDS); optionally writes fp32 scalar (m=0,n=0) to finalOut.
template <int MT>
__device__ __forceinline__ void out_layer(
    const unsigned short* Ah, const unsigned short* Al,
    const unsigned short* __restrict__ WTh, const unsigned short* __restrict__ WTl,
    const float* __restrict__ bias,
    unsigned short* outH, unsigned short* outL, float* finalOut)
{
  const int tid  = threadIdx.x;
  const int wave = tid >> 6;
  const int lane = tid & 63;
  const int quad = lane >> 4;
  const int l16  = lane & 15;
  if (wave < 3) {                       // 48 padded cols cover 33
    const int n_row = wave * 16 + l16;
    short8 wh[4], wl[4];
#pragma unroll
    for (int kc = 0; kc < 4; ++kc) {
      wh[kc] = *(const short8*)&WTh[n_row * KSTR + kc * 32 + quad * 8];
      wl[kc] = *(const short8*)&WTl[n_row * KSTR + kc * 32 + quad * 8];
    }
    const int nb = wave * 16 + quad * 4;
    const float4 bv = *(const float4*)&bias[nb];
    const float bvr[4] = {bv.x, bv.y, bv.z, bv.w};

    f32x4 c[MT];
#pragma unroll
    for (int mt = 0; mt < MT; ++mt) c[mt] = (f32x4){0.f, 0.f, 0.f, 0.f};
#pragma unroll
    for (int kc = 0; kc < 4; ++kc) {
      const int k0 = kc * 32 + quad * 8;
#pragma unroll
      for (int mt = 0; mt < MT; ++mt) {
        const short8 ah = *(const short8*)&Ah[(mt * 16 + l16) * KSTR + k0];
        const short8 al = *(const short8*)&Al[(mt * 16 + l16) * KSTR + k0];
        c[mt] = __builtin_amdgcn_mfma_f32_16x16x32_bf16(wh[kc], ah, c[mt], 0, 0, 0);
        c[mt] = __builtin_amdgcn_mfma_f32_16x16x32_bf16(wh[kc], al, c[mt], 0, 0, 0);
        c[mt] = __builtin_amdgcn_mfma_f32_16x16x32_bf16(wl[kc], ah, c[mt], 0, 0, 0);
      }
    }
#pragma unroll
    for (int mt = 0; mt < MT; ++mt) {
      const int m = mt * 16 + l16;
#pragma unroll
      for (int r = 0; r < 4; ++r) {
        const int n = nb + r;
        const float v = c[mt][r] + bvr[r];
        if (n < OUTC) {
          outH[m * 33 + n] = (unsigned short)(__float_as_uint(v) >> 16);
          outL[m * 33 + n] = f2bf_rne(v - trunc_bf(v));
        }
        if (finalOut && n == 0 && m == 0) *finalOut = v;
      }
    }
  }
}

__global__ __launch_bounds__(THREADS, 4)
void leaf_kernel(const float* __restrict__ X,
                 const unsigned short* __restrict__ warena,
                 const float* __restrict__ barena,
                 unsigned short* __restrict__ outH, unsigned short* __restrict__ outL)
{
  __shared__ unsigned short Ah[64 * KSTR];
  __shared__ unsigned short Al[64 * KSTR];
  const int row_base = blockIdx.x * 64;
  const int tid = threadIdx.x;

  for (int e = tid; e < 64 * 16; e += THREADS) {
    const int r  = e >> 4;
    const int k0 = (e & 15) << 2;
    const float4 v = *(const float4*)&X[(size_t)(row_base + r) * FLEAF + k0];
    const unsigned int h0 = pack_hi_trunc(v.x, v.y);
    const unsigned int h1 = pack_hi_trunc(v.z, v.w);
    const unsigned int l0 = pack_lo_rne(v.x - trunc_bf(v.x), v.y - trunc_bf(v.y));
    const unsigned int l1 = pack_lo_rne(v.z - trunc_bf(v.z), v.w - trunc_bf(v.w));
    *(uint2*)&Ah[r * KSTR + k0] = make_uint2(h0, h1);
    *(uint2*)&Al[r * KSTR + k0] = make_uint2(l0, l1);
  }
  __syncthreads();

  dense_layer<2, 4>(Ah, Al, warena + 0 * 2 * MATSZ, warena + 0 * 2 * MATSZ + MATSZ, barena + 0 * 128);
#pragma unroll
  for (int l = 0; l < 4; ++l) {
    const int id = 1 + l;
    dense_layer<4, 4>(Ah, Al, warena + id * 2 * MATSZ, warena + id * 2 * MATSZ + MATSZ, barena + id * 128);
  }
  out_layer<4>(Ah, Al, warena + 5 * 2 * MATSZ, warena + 5 * 2 * MATSZ + MATSZ, barena + 5 * 128,
               outH + (size_t)row_base * 33, outL + (size_t)row_base * 33, nullptr);
}

__global__ __launch_bounds__(THREADS, 4)
void int_kernel(const float* __restrict__ feat,
                const unsigned short* __restrict__ prevH, const unsigned short* __restrict__ prevL,
                const unsigned short* __restrict__ warena, const float* __restrict__ barena,
                unsigned short* __restrict__ outH, unsigned short* __restrict__ outL,
                int n, int logn)
{
  __shared__ unsigned short Ah[64 * KSTR];
  __shared__ unsigned short Al[64 * KSTR];
  const int tid = threadIdx.x;
  const int m = tid & 63;
  const int g = tid >> 6;
  const int row = blockIdx.x * 64 + m;
  const int b = row >> logn;
  const int i = row & (n - 1);

  // feat: 32 fp32 -> 16 float2 chunks, convert + packed u32 LDS writes
  const float* fr = feat + ((size_t)b * NINT + (n - 1) + i) * FINT;
#pragma unroll
  for (int j = 0; j < 4; ++j) {
    const int cch = g + 4 * j;                         // 0..15
    const float2 v = *(const float2*)&fr[cch * 2];
    *(unsigned int*)&Ah[m * KSTR + cch * 2] = pack_hi_trunc(v.x, v.y);
    *(unsigned int*)&Al[m * KSTR + cch * 2] = pack_lo_rne(v.x - trunc_bf(v.x), v.y - trunc_bf(v.y));
  }
  // children: rows 2i,2i+1 are 66 contiguous u16 in prev (c0 always even -> u32 copies)
  const size_t c0 = ((size_t)b * (n << 1) + (i << 1)) * 33;
#pragma unroll
  for (int j = 0; j < 9; ++j) {
    const int p = g + 4 * j;                           // 0..35
    if (p < 33) {
      const unsigned int hv = *(const unsigned int*)&prevH[c0 + 2 * p];
      const unsigned int lv = *(const unsigned int*)&prevL[c0 + 2 * p];
      *(unsigned int*)&Ah[m * KSTR + 32 + 2 * p] = hv;
      *(unsigned int*)&Al[m * KSTR + 32 + 2 * p] = lv;
    }
  }
  // zero-pad k = 98..127
#pragma unroll
  for (int j = 0; j < 4; ++j) {
    const int p = g + 4 * j;                           // 0..15
    if (p < 15) {
      *(unsigned int*)&Ah[m * KSTR + 98 + 2 * p] = 0u;
      *(unsigned int*)&Al[m * KSTR + 98 + 2 * p] = 0u;
    }
  }
  __syncthreads();

  dense_layer<4, 4>(Ah, Al, warena + 6 * 2 * MATSZ, warena + 6 * 2 * MATSZ + MATSZ, barena + 6 * 128);
#pragma unroll
  for (int l = 0; l < 4; ++l) {
    const int id = 7 + l;
    dense_layer<4, 4>(Ah, Al, warena + id * 2 * MATSZ, warena + id * 2 * MATSZ + MATSZ, barena + id * 128);
  }
  out_layer<4>(Ah, Al, warena + 11 * 2 * MATSZ, warena + 11 * 2 * MATSZ + MATSZ, barena + 11 * 128,
               outH + (size_t)blockIdx.x * 64 * 33, outL + (size_t)blockIdx.x * 64 * 33, nullptr);
}

// Fused tail: levels d=5..0 for one batch per block; inter-level data in LDS.
__global__ __launch_bounds__(THREADS, 4)
void tail_kernel(const float* __restrict__ feat,
                 const unsigned short* __restrict__ g6H, const unsigned short* __restrict__ g6L,
                 const unsigned short* __restrict__ warena, const float* __restrict__ barena,
                 float* __restrict__ out)
{
  __shared__ unsigned short Ah[64 * KSTR];
  __shared__ unsigned short Al[64 * KSTR];
  __shared__ unsigned short oH[64 * 33];
  __shared__ unsigned short oL[64 * 33];
  const int tid = threadIdx.x;
  const int m = tid & 63;
  const int g = tid >> 6;
  const int b = blockIdx.x;

  for (int d = 5; d >= 0; --d) {
    const int n = 1 << d;
    const int i = m & (n - 1);          // clamp; junk rows compute harmless garbage
    const float* fr = feat + ((size_t)b * NINT + (n - 1) + i) * FINT;
#pragma unroll
    for (int j = 0; j < 4; ++j) {
      const int cch = g + 4 * j;
      const float2 v = *(const float2*)&fr[cch * 2];
      *(unsigned int*)&Ah[m * KSTR + cch * 2] = pack_hi_trunc(v.x, v.y);
      *(unsigned int*)&Al[m * KSTR + cch * 2] = pack_lo_rne(v.x - trunc_bf(v.x), v.y - trunc_bf(v.y));
    }
    const unsigned short* sH;
    const unsigned short* sL;
    size_t c0;
    if (d == 5) { sH = g6H; sL = g6L; c0 = ((size_t)b * 64 + 2 * i) * 33; }
    else        { sH = oH;  sL = oL;  c0 = (size_t)(2 * i) * 33; }
#pragma unroll
    for (int j = 0; j < 9; ++j) {
      const int p = g + 4 * j;
      if (p < 33) {
        const unsigned int hv = *(const unsigned int*)&sH[c0 + 2 * p];
        const unsigned int lv = *(const unsigned int*)&sL[c0 + 2 * p];
        *(unsigned int*)&Ah[m * KSTR + 32 + 2 * p] = hv;
        *(unsigned int*)&Al[m * KSTR + 32 + 2 * p] = lv;
      }
    }
#pragma unroll
    for (int j = 0; j < 4; ++j) {
      const int p = g + 4 * j;
      if (p < 15) {
        *(unsigned int*)&Ah[m * KSTR + 98 + 2 * p] = 0u;
        *(unsigned int*)&Al[m * KSTR + 98 + 2 * p] = 0u;
      }
    }
    __syncthreads();

    if (d == 5) {
      dense_layer<4, 2>(Ah, Al, warena + 6 * 2 * MATSZ, warena + 6 * 2 * MATSZ + MATSZ, barena + 6 * 128);
#pragma unroll
      for (int l = 0; l < 4; ++l) {
        const int id = 7 + l;
        dense_layer<4, 2>(Ah, Al, warena + id * 2 * MATSZ, warena + id * 2 * MATSZ + MATSZ, barena + id * 128);
      }
      out_layer<2>(Ah, Al, warena + 11 * 2 * MATSZ, warena + 11 * 2 * MATSZ + MATSZ, barena + 11 * 128,
                   oH, oL, nullptr);
    } else {
      dense_layer<4, 1>(Ah, Al, warena + 6 * 2 * MATSZ, warena + 6 * 2 * MATSZ + MATSZ, barena + 6 * 128);
#pragma unroll
      for (int l = 0; l < 4; ++l) {
        const int id = 7 + l;
        dense_layer<4, 1>(Ah, Al, warena + id * 2 * MATSZ, warena + id * 2 * MATSZ + MATSZ, barena + id * 128);
      }
      out_layer<1>(Ah, Al, warena + 11 * 2 * MATSZ, warena + 11 * 2 * MATSZ + MATSZ, barena + 11 * 128,
                   oH, oL, (d == 0) ? (out + b) : nullptr);
    }
    __syncthreads();   // out_layer reads/writes done before next staging
  }
}

// Pre-transpose + hi/lo split 12 weight matrices into WT[n][KSTR] (RNE both halves),
// pack biases zero-padded to 128.
__global__ void prep_kernel(const float* __restrict__ lW_in, const float* __restrict__ lW_hid,
                            const float* __restrict__ lW_out, const float* __restrict__ lb_in,
                            const float* __restrict__ lb_hid, const float* __restrict__ lb_out,
                            const float* __restrict__ iW_in, const float* __restrict__ iW_hid,
                            const float* __restrict__ iW_out, const float* __restrict__ ib_in,
                            const float* __restrict__ ib_hid, const float* __restrict__ ib_out,
                            unsigned short* __restrict__ warena, float* __restrict__ barena)
{
  const int id = blockIdx.y;
  const float* W; const float* bs; int K, N;
  if (id == 0)       { W = lW_in;                        bs = lb_in;                 K = FLEAF; N = Hh; }
  else if (id <= 4)  { W = lW_hid + (id - 1) * Hh * Hh;  bs = lb_hid + (id - 1) * Hh; K = Hh;   N = Hh; }
  else if (id == 5)  { W = lW_out;                       bs = lb_out;                K = Hh;    N = OUTC; }
  else if (id == 6)  { W = iW_in;                        bs = ib_in;                 K = FINT + 2 * OUTC; N = Hh; }
  else if (id <= 10) { W = iW_hid + (id - 7) * Hh * Hh;  bs = ib_hid + (id - 7) * Hh; K = Hh;   N = Hh; }
  else               { W = iW_out;                       bs = ib_out;                K = Hh;    N = OUTC; }

  unsigned short* dh = warena + id * 2 * MATSZ;
  unsigned short* dl = dh + MATSZ;
  const int e = blockIdx.x * THREADS + threadIdx.x;
  if (e < MATSZ) {
    const int nn = e / KSTR;
    const int kk = e - nn * KSTR;
    const float v = (kk < K && nn < N) ? W[(size_t)kk * N + nn] : 0.f;
    const unsigned short h = f2bf_rne(v);
    dh[e] = h;
    dl[e] = f2bf_rne(v - bf2f(h));
  }
  if (blockIdx.x == 0 && threadIdx.x < 128)
    barena[id * 128 + threadIdx.x] = (threadIdx.x < N) ? bs[threadIdx.x] : 0.f;
}

extern "C" void kernel_launch(void* const* d_in, const int* in_sizes, int n_in,
                              void* d_out, int out_size, void* d_ws, size_t ws_size,
                              hipStream_t stream) {
  const float* leaf_feat = (const float*)d_in[0];
  const float* int_feat  = (const float*)d_in[1];
  const float* lW_in  = (const float*)d_in[2];
  const float* lb_in  = (const float*)d_in[3];
  const float* lW_hid = (const float*)d_in[4];
  const float* lb_hid = (const float*)d_in[5];
  const float* lW_out = (const float*)d_in[6];
  const float* lb_out = (const float*)d_in[7];
  const float* iW_in  = (const float*)d_in[8];
  const float* ib_in  = (const float*)d_in[9];
  const float* iW_hid = (const float*)d_in[10];
  const float* ib_hid = (const float*)d_in[11];
  const float* iW_out = (const float*)d_in[12];
  const float* ib_out = (const float*)d_in[13];
  float* out = (float*)d_out;

  // ws layout (u16 hi/lo stage buffers, stride 33):
  //  A: 524288 rows (leaf out / d8 out / d6 out), B: 262144 rows (d9 out / d7 out)
  const size_t rowsA = (size_t)Bn * LEAVES;       // 524288
  const size_t rowsB = rowsA / 2;                 // 262144
  unsigned short* AH = (unsigned short*)d_ws;
  unsigned short* AL = AH + rowsA * 33;
  unsigned short* BH = AL + rowsA * 33;
  unsigned short* BL = BH + rowsB * 33;
  unsigned short* warena = BL + rowsB * 33;
  float* barena = (float*)(warena + 24 * MATSZ);  // total ~104.7 MB

  prep_kernel<<<dim3((MATSZ + THREADS - 1) / THREADS, 12), THREADS, 0, stream>>>(
      lW_in, lW_hid, lW_out, lb_in, lb_hid, lb_out,
      iW_in, iW_hid, iW_out, ib_in, ib_hid, ib_out, warena, barena);

  leaf_kernel<<<(Bn * LEAVES) / 64, THREADS, 0, stream>>>(leaf_feat, warena, barena, AH, AL);

  int_kernel<<<4096, THREADS, 0, stream>>>(int_feat, AH, AL, warena, barena, BH, BL, 512, 9);
  int_kernel<<<2048, THREADS, 0, stream>>>(int_feat, BH, BL, warena, barena, AH, AL, 256, 8);
  int_kernel<<<1024, THREADS, 0, stream>>>(int_feat, AH, AL, warena, barena, BH, BL, 128, 7);
  int_kernel<<< 512, THREADS, 0, stream>>>(int_feat, BH, BL, warena, barena, AH, AL,  64, 6);

  tail_kernel<<<Bn, THREADS, 0, stream>>>(int_feat, AH, AL, warena, barena, out);
}